// Round 4
// baseline (203.828 us; speedup 1.0000x reference)
//
#include <hip/hip_runtime.h>
#include <hip/hip_bf16.h>

// VQ-VAE quantizer via bf16 MFMA, LDS-free latency-oriented version.
// lat [64,64,64,64] f32, emb [512,64] f32.
// score(n,k) = 0.5||e_k||^2 - l_n.e_k  (argmin-equiv to sq-distance)
// loss = 1.25/(N*D) * sum_n (||l_n||^2 + 2*score_best(n))
// cc folded into the MFMA chain: acc0 = mfma(aone, bcc, 0) where
// aone[row][k]=delta(k,0), bcc[k][col]=delta(k,0)*cc_col. Argmin via
// monotone float key (low 9 mantissa bits := code) + v_min_f32.

#define KCODES 512
#define DDIM   64
#define HW     4096
#define BHW    262144      // DDIM*HW
#define EMB_OFF 1024       // ws byte offset: bf16 emb [512][64] (64 KB)
#define BCC_OFF 66560      // ws byte offset: bcc frag table [32][64]x16B (32 KB)

typedef __bf16 bf16x8 __attribute__((ext_vector_type(8)));
typedef float  f32x4  __attribute__((ext_vector_type(4)));

// ---- prep: emb f32 -> bf16 table + cc fragment table (runs once per call)
__global__ __launch_bounds__(512) void vq_prep(const float* __restrict__ emb,
                                               char* __restrict__ ws) {
  __shared__ float ccs[KCODES];
  const int tid = threadIdx.x;

  // zero the bcc region (32 KB): 512 threads x 64 B
  {
    f32x4 z = {0.f, 0.f, 0.f, 0.f};
    f32x4* bz = (f32x4*)(ws + BCC_OFF);
#pragma unroll
    for (int r = 0; r < 4; ++r) bz[tid * 4 + r] = z;
  }

  // convert emb to bf16 (granule = 8 floats) + cc = 0.5||e||^2 via 8-lane reduce
  __bf16* ebf = (__bf16*)(ws + EMB_OFF);
#pragma unroll
  for (int r = 0; r < 8; ++r) {
    int G = tid + 512 * r;            // 0..4095 = code*8 + gr
    int code = G >> 3;
    const float4* s = (const float4*)(emb + G * 8);
    float4 x = s[0], y = s[1];
    bf16x8 h;
    h[0] = (__bf16)x.x; h[1] = (__bf16)x.y; h[2] = (__bf16)x.z; h[3] = (__bf16)x.w;
    h[4] = (__bf16)y.x; h[5] = (__bf16)y.y; h[6] = (__bf16)y.z; h[7] = (__bf16)y.w;
    *(bf16x8*)(ebf + G * 8) = h;
    float p = x.x*x.x + x.y*x.y + x.z*x.z + x.w*x.w
            + y.x*y.x + y.y*y.y + y.z*y.z + y.w*y.w;
    p += __shfl_xor(p, 1); p += __shfl_xor(p, 2); p += __shfl_xor(p, 4);
    if ((tid & 7) == 0) ccs[code] = 0.5f * p;
  }
  __syncthreads();

  // bcc[c][lane] = (lane<16) ? bf16(cc[c*16+lane]) at slot 0 : zeros
  {
    int c = tid >> 4, l = tid & 15;   // tid == code
    __bf16* slot = (__bf16*)(ws + BCC_OFF + (c * 64 + l) * 16);
    *slot = (__bf16)ccs[tid];
  }
}

// ---- main: no LDS, no barrier. 1 wave = 64 positions (4 MFMA tiles).
__global__ __launch_bounds__(256, 4) void vq_main(
    const float* __restrict__ lat,
    const float* __restrict__ emb,
    float* __restrict__ out,
    char* __restrict__ ws) {
  const int tid  = threadIdx.x;
  const int lane = tid & 63;
  const int wid  = tid >> 6;
  const int L15  = lane & 15;          // A-row(pos) / B-col(code)
  const int g    = lane >> 4;          // k-octet selector

  const int gw    = blockIdx.x * 4 + wid;     // 0..4095
  const int nb0   = gw * 64;
  const int bslab = nb0 >> 12;
  const int hw0   = nb0 & 4095;               // 64-aligned
  const float* __restrict__ lbase = lat + bslab * BHW + hw0 + L15;

  // A fragments (negated bf16) + fp32 ||l||^2 partial
  float  l2_acc = 0.f;
  bf16x8 af[4][2];
#pragma unroll
  for (int t = 0; t < 4; ++t) {
    const float* lt = lbase + t * 16;
#pragma unroll
    for (int kk = 0; kk < 2; ++kk) {
#pragma unroll
      for (int i = 0; i < 8; ++i) {
        float v = lt[(kk * 32 + g * 8 + i) * HW];
        l2_acc = fmaf(v, v, l2_acc);
        af[t][kk][i] = (__bf16)(-v);
      }
    }
  }

  // aone: A[row][k] = delta(k,0)
  bf16x8 aone = {};
  aone[0] = (g == 0) ? (__bf16)1.0f : (__bf16)0.0f;
  const f32x4 fzero = {0.f, 0.f, 0.f, 0.f};

  const char* __restrict__ eb = ws + EMB_OFF;   // bf16 [512][64]
  const char* __restrict__ bc = ws + BCC_OFF;   // [32][64] x 16B

  float bv[4][4];     // monotone float keys (score with code in low 9 bits)
#pragma unroll
  for (int t = 0; t < 4; ++t)
#pragma unroll
    for (int j = 0; j < 4; ++j) bv[t][j] = 3.0e38f;

  unsigned codev = (unsigned)L15;

  for (int c = 0; c < 32; ++c) {
    const char* ebc = eb + c * 2048 + L15 * 128 + g * 16;
    bf16x8 b0  = *(const bf16x8*)(ebc);
    bf16x8 b1  = *(const bf16x8*)(ebc + 64);
    bf16x8 bcc = *(const bf16x8*)(bc + c * 1024 + lane * 16);
    f32x4 acc0 = __builtin_amdgcn_mfma_f32_16x16x32_bf16(aone, bcc, fzero, 0, 0, 0);
#pragma unroll
    for (int t = 0; t < 4; ++t) {
      f32x4 a1 = __builtin_amdgcn_mfma_f32_16x16x32_bf16(af[t][0], b0, acc0, 0, 0, 0);
      f32x4 a2 = __builtin_amdgcn_mfma_f32_16x16x32_bf16(af[t][1], b1, a1,   0, 0, 0);
#pragma unroll
      for (int j = 0; j < 4; ++j) {
        unsigned key = (__float_as_uint(a2[j]) & 0xFFFFFE00u) | codev;
        bv[t][j] = fminf(bv[t][j], __uint_as_float(key));
      }
    }
    codev += 16u;
  }

  // epilogue: per tile, 16-lane float-key min reduce; redistribute; gather
  float ssum = 0.f;   // per-lane row-best score, x4 duplicated over g
#pragma unroll
  for (int t = 0; t < 4; ++t) {
    float kk4[4];
#pragma unroll
    for (int j = 0; j < 4; ++j) {
      float v = bv[t][j];
#pragma unroll
      for (int m = 1; m < 16; m <<= 1) v = fminf(v, __shfl_xor(v, m));
      kk4[j] = v;                    // best for row 4g+j, uniform in group
    }
    const int src = (L15 >> 2) << 4; // lane serving row L15: group L15>>2
    float r0 = __shfl(kk4[0], src), r1 = __shfl(kk4[1], src);
    float r2 = __shfl(kk4[2], src), r3 = __shfl(kk4[3], src);
    float k01 = (L15 & 1) ? r1 : r0;
    float k23 = (L15 & 1) ? r3 : r2;
    float kf  = (L15 & 2) ? k23 : k01;
    unsigned kb  = __float_as_uint(kf);
    const int myk = (int)(kb & 0x1FFu);
    ssum += __uint_as_float(kb & 0xFFFFFE00u);   // truncated best score

    const int dbase = g * 16;
    const float4* q = (const float4*)(emb + myk * 64 + dbase);
    float* ob = out + bslab * BHW + dbase * HW + hw0 + t * 16 + L15;
#pragma unroll
    for (int p4 = 0; p4 < 4; ++p4) {
      float4 vq = q[p4];
      ob[(4 * p4 + 0) * HW] = vq.x;
      ob[(4 * p4 + 1) * HW] = vq.y;
      ob[(4 * p4 + 2) * HW] = vq.z;
      ob[(4 * p4 + 3) * HW] = vq.w;
    }
  }

  // loss partial: Sum l2 + 2*Sum bestv ; ssum counts each pos 4x -> *0.5
  float p = fmaf(0.5f, ssum, l2_acc);
#pragma unroll
  for (int off = 32; off; off >>= 1) p += __shfl_down(p, off);
  if (lane == 0) atomicAdd((float*)ws, p);
}

__global__ void vq_finish(const char* __restrict__ ws,
                          float* __restrict__ out, int out_size) {
  out[out_size - 1] = ((const float*)ws)[0] * (1.25f / 16777216.0f);
}

extern "C" void kernel_launch(void* const* d_in, const int* in_sizes, int n_in,
                              void* d_out, int out_size, void* d_ws, size_t ws_size,
                              hipStream_t stream) {
  const float* lat = (const float*)d_in[0];
  const float* emb = (const float*)d_in[1];
  float* out = (float*)d_out;
  char* ws = (char*)d_ws;

  hipMemsetAsync(d_ws, 0, 4, stream);
  vq_prep<<<1, 512, 0, stream>>>(emb, ws);
  vq_main<<<1024, 256, 0, stream>>>(lat, emb, out, ws);
  vq_finish<<<1, 1, 0, stream>>>(ws, out, out_size);
}

// Round 5
// 193.424 us; speedup vs baseline: 1.0538x; 1.0538x over previous
//
#include <hip/hip_runtime.h>
#include <hip/hip_bf16.h>

// VQ-VAE quantizer via bf16 MFMA, LDS-free, spill-free, prefetch-1.
// lat [64,64,64,64] f32, emb [512,64] f32.
// score(n,k) = 0.5||e_k||^2 - l_n.e_k  (argmin-equiv to sq-distance)
// loss = 1.25/(N*D) * sum_n (||l_n||^2 + 2*score_best(n))
// cc folded via acc0 = mfma(aone, bcc, 0); argmin via monotone float key
// (low 9 mantissa bits := code) reduced with v_min_f32.

#define KCODES 512
#define DDIM   64
#define HW     4096
#define BHW    262144      // DDIM*HW
#define EMB_OFF 1024       // ws: bf16 emb [512][64] (64 KB)
#define BCC_OFF 66560      // ws: bcc frag table [32][64]x16B (32 KB)

typedef __bf16 bf16x8 __attribute__((ext_vector_type(8)));
typedef float  f32x4  __attribute__((ext_vector_type(4)));

// ---- prep: emb f32 -> bf16 table + cc fragment table
__global__ __launch_bounds__(512) void vq_prep(const float* __restrict__ emb,
                                               char* __restrict__ ws) {
  __shared__ float ccs[KCODES];
  const int tid = threadIdx.x;

  {  // zero bcc region (32 KB)
    f32x4 z = {0.f, 0.f, 0.f, 0.f};
    f32x4* bz = (f32x4*)(ws + BCC_OFF);
#pragma unroll
    for (int r = 0; r < 4; ++r) bz[tid * 4 + r] = z;
  }

  __bf16* ebf = (__bf16*)(ws + EMB_OFF);
#pragma unroll
  for (int r = 0; r < 8; ++r) {
    int G = tid + 512 * r;            // 0..4095 = code*8 + gr
    int code = G >> 3;
    const float4* s = (const float4*)(emb + G * 8);
    float4 x = s[0], y = s[1];
    bf16x8 h;
    h[0] = (__bf16)x.x; h[1] = (__bf16)x.y; h[2] = (__bf16)x.z; h[3] = (__bf16)x.w;
    h[4] = (__bf16)y.x; h[5] = (__bf16)y.y; h[6] = (__bf16)y.z; h[7] = (__bf16)y.w;
    *(bf16x8*)(ebf + G * 8) = h;
    float p = x.x*x.x + x.y*x.y + x.z*x.z + x.w*x.w
            + y.x*y.x + y.y*y.y + y.z*y.z + y.w*y.w;
    p += __shfl_xor(p, 1); p += __shfl_xor(p, 2); p += __shfl_xor(p, 4);
    if ((tid & 7) == 0) ccs[code] = 0.5f * p;
  }
  __syncthreads();

  {  // bcc[c][lane<16] slot0 = bf16(cc[c*16+lane])
    int c = tid >> 4, l = tid & 15;   // tid == code
    __bf16* slot = (__bf16*)(ws + BCC_OFF + (c * 64 + l) * 16);
    *slot = (__bf16)ccs[tid];
  }
}

// ---- main: no LDS, no barrier. 1 wave = 64 positions (4 MFMA tiles).
// launch_bounds(256,2): VGPR cap 256 -> allocator must NOT round down to 64
// and spill (rounds 2 & 4 lost 25-55 us to exactly that; round 3's (512,2)
// -> 84 VGPR no-spill is the known-good pattern).
__global__ __launch_bounds__(256, 2) void vq_main(
    const float* __restrict__ lat,
    const float* __restrict__ emb,
    float* __restrict__ out,
    char* __restrict__ ws) {
  const int tid  = threadIdx.x;
  const int lane = tid & 63;
  const int wid  = tid >> 6;
  const int L15  = lane & 15;          // A-row(pos) / B-col(code)
  const int g    = lane >> 4;          // k-octet selector

  const int gw    = blockIdx.x * 4 + wid;     // 0..4095
  const int nb0   = gw * 64;
  const int bslab = nb0 >> 12;
  const int hw0   = nb0 & 4095;               // 64-aligned
  const float* __restrict__ lbase = lat + bslab * BHW + hw0 + L15;

  // A fragments (negated bf16) + fp32 ||l||^2 partial
  float  l2_acc = 0.f;
  bf16x8 af[4][2];
#pragma unroll
  for (int t = 0; t < 4; ++t) {
    const float* lt = lbase + t * 16;
#pragma unroll
    for (int kk = 0; kk < 2; ++kk) {
#pragma unroll
      for (int i = 0; i < 8; ++i) {
        float v = lt[(kk * 32 + g * 8 + i) * HW];
        l2_acc = fmaf(v, v, l2_acc);
        af[t][kk][i] = (__bf16)(-v);
      }
    }
  }

  // aone: A[row][k] = delta(k,0)
  bf16x8 aone = {};
  aone[0] = (g == 0) ? (__bf16)1.0f : (__bf16)0.0f;
  const f32x4 fzero = {0.f, 0.f, 0.f, 0.f};

  const char* __restrict__ pb = ws + EMB_OFF + L15 * 128 + g * 16; // b stream
  const char* __restrict__ pc = ws + BCC_OFF + lane * 16;          // bcc stream

  float bv[4][4];     // monotone float keys (score | code in low 9 bits)
#pragma unroll
  for (int t = 0; t < 4; ++t)
#pragma unroll
    for (int j = 0; j < 4; ++j) bv[t][j] = 3.0e38f;

  unsigned codev = (unsigned)L15;

  // distance-1 prefetched main loop (loads for c+1 issue before compute of c;
  // (c+1)&31 wraps so loads are unconditional and always in-bounds)
  bf16x8 b0  = *(const bf16x8*)(pb);
  bf16x8 b1  = *(const bf16x8*)(pb + 64);
  bf16x8 bcc = *(const bf16x8*)(pc);
  for (int c = 0; c < 32; ++c) {
    const int cn = (c + 1) & 31;
    bf16x8 n0  = *(const bf16x8*)(pb + cn * 2048);
    bf16x8 n1  = *(const bf16x8*)(pb + cn * 2048 + 64);
    bf16x8 ncc = *(const bf16x8*)(pc + cn * 1024);

    f32x4 acc0 = __builtin_amdgcn_mfma_f32_16x16x32_bf16(aone, bcc, fzero, 0, 0, 0);
#pragma unroll
    for (int t = 0; t < 4; ++t) {
      f32x4 a1 = __builtin_amdgcn_mfma_f32_16x16x32_bf16(af[t][0], b0, acc0, 0, 0, 0);
      f32x4 a2 = __builtin_amdgcn_mfma_f32_16x16x32_bf16(af[t][1], b1, a1,   0, 0, 0);
#pragma unroll
      for (int j = 0; j < 4; ++j) {
        unsigned key = (__float_as_uint(a2[j]) & 0xFFFFFE00u) | codev;
        bv[t][j] = fminf(bv[t][j], __uint_as_float(key));
      }
    }
    codev += 16u;
    b0 = n0; b1 = n1; bcc = ncc;
  }

  // epilogue: per tile, 16-lane float-key min reduce; redistribute; gather
  float ssum = 0.f;   // per-lane row-best score, x4 duplicated over g
#pragma unroll
  for (int t = 0; t < 4; ++t) {
    float kk4[4];
#pragma unroll
    for (int j = 0; j < 4; ++j) {
      float v = bv[t][j];
#pragma unroll
      for (int m = 1; m < 16; m <<= 1) v = fminf(v, __shfl_xor(v, m));
      kk4[j] = v;                    // best for row 4g+j, uniform in group
    }
    const int src = (L15 >> 2) << 4; // lane serving row L15: group L15>>2
    float r0 = __shfl(kk4[0], src), r1 = __shfl(kk4[1], src);
    float r2 = __shfl(kk4[2], src), r3 = __shfl(kk4[3], src);
    float k01 = (L15 & 1) ? r1 : r0;
    float k23 = (L15 & 1) ? r3 : r2;
    float kf  = (L15 & 2) ? k23 : k01;
    unsigned kb  = __float_as_uint(kf);
    const int myk = (int)(kb & 0x1FFu);
    ssum += __uint_as_float(kb & 0xFFFFFE00u);   // truncated best score

    const int dbase = g * 16;
    const float4* q = (const float4*)(emb + myk * 64 + dbase);
    float* ob = out + bslab * BHW + dbase * HW + hw0 + t * 16 + L15;
#pragma unroll
    for (int p4 = 0; p4 < 4; ++p4) {
      float4 vq = q[p4];
      ob[(4 * p4 + 0) * HW] = vq.x;
      ob[(4 * p4 + 1) * HW] = vq.y;
      ob[(4 * p4 + 2) * HW] = vq.z;
      ob[(4 * p4 + 3) * HW] = vq.w;
    }
  }

  // loss partial: Sum l2 + 2*Sum bestv ; ssum counts each pos 4x -> *0.5
  float p = fmaf(0.5f, ssum, l2_acc);
#pragma unroll
  for (int off = 32; off; off >>= 1) p += __shfl_down(p, off);
  if (lane == 0) atomicAdd((float*)ws, p);
}

__global__ void vq_finish(const char* __restrict__ ws,
                          float* __restrict__ out, int out_size) {
  out[out_size - 1] = ((const float*)ws)[0] * (1.25f / 16777216.0f);
}

extern "C" void kernel_launch(void* const* d_in, const int* in_sizes, int n_in,
                              void* d_out, int out_size, void* d_ws, size_t ws_size,
                              hipStream_t stream) {
  const float* lat = (const float*)d_in[0];
  const float* emb = (const float*)d_in[1];
  float* out = (float*)d_out;
  char* ws = (char*)d_ws;

  hipMemsetAsync(d_ws, 0, 4, stream);
  vq_prep<<<1, 512, 0, stream>>>(emb, ws);
  vq_main<<<1024, 256, 0, stream>>>(lat, emb, out, ws);
  vq_finish<<<1, 1, 0, stream>>>(ws, out, out_size);
}